// Round 6
// baseline (175.432 us; speedup 1.0000x reference)
//
#include <hip/hip_runtime.h>
#include <hip/hip_bf16.h>

// GAT attention aggregator, fused+persistent. B=20000, N=32, D=128, H=256, O=128.
// R6: 1024 persistent blocks (4/CU), each loops ~5 node-groups (MB=4).
// Next-group staging (HBM) overlaps the current group's final matmul.
// ks-outer MFMA + single reused weight-panel array keeps VGPR <= 128.

#define BB 20000
#define NN 32
#define DD 128
#define HH 256
#define OO 128
#define MB 4
#define NGROUP (BB / MB)   // 5000
#define GRID 1024
#define ROWS 144           // 128 neib + [x_p0 | agg | x_p1 | junk] tile rows 128..143
#define AG0 132

typedef __bf16 bf16x8 __attribute__((ext_vector_type(8)));
typedef __bf16 bf16x4 __attribute__((ext_vector_type(4)));
typedef float f32x4 __attribute__((ext_vector_type(4)));

template<int CTRL>
__device__ __forceinline__ float dpp_add(float v) {
    int r = __builtin_amdgcn_update_dpp(0, __builtin_bit_cast(int, v), CTRL, 0xF, 0xF, true);
    return v + __builtin_bit_cast(float, r);
}
// lane 15 of each 16-lane row ends with the row sum
__device__ __forceinline__ float red16(float v) {
    v = dpp_add<0x111>(v);
    v = dpp_add<0x112>(v);
    v = dpp_add<0x114>(v);
    v = dpp_add<0x118>(v);
    return v;
}

__global__ void prep_weights(const float* __restrict__ Watt,
                             const float* __restrict__ Wfcx,
                             const float* __restrict__ Wfcn,
                             __bf16* __restrict__ WaT,
                             __bf16* __restrict__ WcT) {
    int idx = blockIdx.x * 256 + threadIdx.x;   // 0..65535
    int half = idx >> 15;
    int j = idx & 32767;
    int c = j >> 7, k = j & 127;
    if (half == 0) {
        WaT[j] = (__bf16)Watt[k * HH + c];       // WaT[h][k] = W_att[k][h]
    } else {
        float wv = (c < OO) ? Wfcx[k * OO + c] : Wfcn[k * OO + (c - OO)];
        WcT[j] = (__bf16)wv;                     // WcT[c][k]
    }
}

__launch_bounds__(256, 4)
__global__ void gat_fused(const float* __restrict__ x,
                          const float* __restrict__ neibs,
                          const float* __restrict__ a,
                          const __bf16* __restrict__ WaT,
                          const __bf16* __restrict__ WcT,
                          float* __restrict__ out) {
    __shared__ __bf16 rowsS[ROWS * 128];         // 36,864 B, XOR-swizzled rows
    __shared__ float e_part[4][ROWS];            //  2,304 B
    __shared__ float att_s[MB][NN];              //    512 B

    const int tid = threadIdx.x;
    const int w   = tid >> 6;
    const int l   = tid & 63;
    const int lr  = l & 15;
    const int lg  = l >> 4;
    char* rbase = (char*)rowsS;

    // persistent per-lane constants
    // staging: row = it*8 + (tid>>5); byte (row*256 + 2k) ^ ((row&7)<<4)
    const int stbase = (tid >> 5) * 256 + ((8 * (tid & 31)) ^ ((tid >> 5) << 4));
    int abase[4];
#pragma unroll
    for (int ks = 0; ks < 4; ++ks)
        abase[ks] = lr * 256 + ((ks * 64 + lg * 16) ^ ((lr & 7) << 4));
    float aX[4], aN[4];
#pragma unroll
    for (int c4 = 0; c4 < 4; ++c4) {
        int col = (w * 4 + c4) * 16 + lr;
        aX[c4] = a[col];
        aN[c4] = a[HH + col];
    }

    int g = (int)blockIdx.x;
    int p = 0;

    // ---- prologue: stage group g ----
    {
        const float4* np4 = (const float4*)(neibs + (size_t)g * MB * NN * DD);
#pragma unroll
        for (int it = 0; it < 16; ++it) {
            float4 v = np4[it * 256 + tid];
            bf16x4 s = { (__bf16)v.x, (__bf16)v.y, (__bf16)v.z, (__bf16)v.w };
            *(bf16x4*)(rbase + stbase + it * 2048) = s;
        }
        if (tid < 128) {                         // x rows 128..131 (p=0)
            float4 v = ((const float4*)(x + (size_t)g * MB * DD))[tid];
            bf16x4 s = { (__bf16)v.x, (__bf16)v.y, (__bf16)v.z, (__bf16)v.w };
            *(bf16x4*)(rbase + stbase + 32768) = s;
        }
    }

    for (;;) {
        __syncthreads();                          // B1: staged data visible

        // ---- score: [144x128] @ WaT^T, fused lrelu(.01)*a + DPP reduce ----
        bf16x8 bw[4][4];                          // W_att panel (reused later for WcT)
#pragma unroll
        for (int c4 = 0; c4 < 4; ++c4)
#pragma unroll
            for (int ks = 0; ks < 4; ++ks)
                bw[c4][ks] = *(const bf16x8*)(WaT + ((w * 4 + c4) * 16 + lr) * 128 + ks * 32 + lg * 8);
        const int xoff = (lr < 4) ? 2048 * p : 0; // x-row double-buffer select

#pragma unroll
        for (int rt = 0; rt < 9; ++rt) {
            f32x4 acc[4];
#pragma unroll
            for (int c4 = 0; c4 < 4; ++c4) acc[c4] = (f32x4){0.f, 0.f, 0.f, 0.f};
#pragma unroll
            for (int ks = 0; ks < 4; ++ks) {
                bf16x8 af = *(const bf16x8*)(rbase + abase[ks] + (rt < 8 ? rt * 4096 : 32768 + xoff));
#pragma unroll
                for (int c4 = 0; c4 < 4; ++c4)
                    acc[c4] = __builtin_amdgcn_mfma_f32_16x16x32_bf16(af, bw[c4][ks], acc[c4], 0, 0, 0);
            }
            float ep[4] = {0.f, 0.f, 0.f, 0.f};
#pragma unroll
            for (int c4 = 0; c4 < 4; ++c4) {
                float av = (rt == 8) ? aX[c4] : aN[c4];
#pragma unroll
                for (int i = 0; i < 4; ++i) {
                    float v = acc[c4][i];
                    float lv = fmaxf(v, 0.f) + 0.01f * fminf(v, 0.f);
                    ep[i] = fmaf(lv, av, ep[i]);
                }
            }
#pragma unroll
            for (int i = 0; i < 4; ++i) ep[i] = red16(ep[i]);
            if (lr == 15) {
                f32x4 st = { ep[0], ep[1], ep[2], ep[3] };
                *(f32x4*)((char*)&e_part[w][0] + rt * 64 + lg * 16) = st;
            }
        }
        __syncthreads();                          // B2: e_part ready

        // ---- softmax over 32 neighbors (threads 0..127) ----
        if (tid < 128) {
            const int bloc = tid >> 5;
            const int nloc = tid & 31;
            float sn = e_part[0][tid] + e_part[1][tid] + e_part[2][tid] + e_part[3][tid];
            int xr = 128 + 8 * p + bloc;
            float sx = e_part[0][xr] + e_part[1][xr] + e_part[2][xr] + e_part[3][xr];
            float e = sx + sn;
            e = (e > 0.f) ? e : 0.2f * e;
            float mx = e;
#pragma unroll
            for (int m = 16; m >= 1; m >>= 1) mx = fmaxf(mx, __shfl_xor(mx, m, 32));
            float ex = __expf(e - mx);
            float sum = ex;
#pragma unroll
            for (int m = 16; m >= 1; m >>= 1) sum += __shfl_xor(sum, m, 32);
            att_s[bloc][nloc] = ex / sum;
        }
        __syncthreads();                          // B3: att_s ready

        // ---- aggregation: wave w = node w; half-waves take even/odd neighbors ----
        {
            const int half = l >> 5, li = l & 31;
            const int agbase = w * 8192 + 256 * half + ((8 * li) ^ (half << 4));
            float ag[4] = {0.f, 0.f, 0.f, 0.f};
#pragma unroll
            for (int i = 0; i < 16; ++i) {
                float wv = att_s[w][2 * i + half];
                bf16x4 v = *(const bf16x4*)(rbase + (agbase ^ ((2 * i & 7) << 4)) + 512 * i);
#pragma unroll
                for (int j = 0; j < 4; ++j) ag[j] = fmaf(wv, (float)v[j], ag[j]);
            }
#pragma unroll
            for (int j = 0; j < 4; ++j) ag[j] += __shfl_xor(ag[j], 32);
            if (half == 0) {
                int row = AG0 + w;                // row&7 = 4+w
                int off = row * 256 + ((8 * li) ^ ((row & 7) << 4));
                bf16x4 s = { (__bf16)ag[0], (__bf16)ag[1], (__bf16)ag[2], (__bf16)ag[3] };
                *(bf16x4*)(rbase + off) = s;
            }
        }
        __syncthreads();                          // B4: agg rows ready; neib region dead

        // ---- overlap region: WcT panel + next-group staging (hides HBM latency
        //      under the final matmul). Benign race: final's lanes lr>=8 read the
        //      x_(p^1)/junk rows being staged — those C rows are masked on store.
        int gn = g + GRID;
        bool more = (gn < NGROUP);
#pragma unroll
        for (int c4 = 0; c4 < 4; ++c4)
#pragma unroll
            for (int ks = 0; ks < 4; ++ks)
                bw[c4][ks] = *(const bf16x8*)(WcT + ((w * 4 + c4) * 16 + lr) * 128 + ks * 32 + lg * 8);
        if (more) {
            const float4* np4 = (const float4*)(neibs + (size_t)gn * MB * NN * DD);
#pragma unroll
            for (int it = 0; it < 16; ++it) {
                float4 v = np4[it * 256 + tid];
                bf16x4 s = { (__bf16)v.x, (__bf16)v.y, (__bf16)v.z, (__bf16)v.w };
                *(bf16x4*)(rbase + stbase + it * 2048) = s;
            }
            if (tid < 128) {                      // next x rows -> other buffer
                float4 v = ((const float4*)(x + (size_t)gn * MB * DD))[tid];
                bf16x4 s = { (__bf16)v.x, (__bf16)v.y, (__bf16)v.z, (__bf16)v.w };
                *(bf16x4*)(rbase + stbase + 32768 + 2048 * (p ^ 1)) = s;
            }
        }

        // ---- final matmul: [x;agg;...](16x128) @ WcT^T(128x256), masked f32 store ----
        {
            f32x4 acc[4];
#pragma unroll
            for (int c4 = 0; c4 < 4; ++c4) acc[c4] = (f32x4){0.f, 0.f, 0.f, 0.f};
#pragma unroll
            for (int ks = 0; ks < 4; ++ks) {
                bf16x8 af = *(const bf16x8*)(rbase + abase[ks] + 32768 + xoff);
#pragma unroll
                for (int c4 = 0; c4 < 4; ++c4)
                    acc[c4] = __builtin_amdgcn_mfma_f32_16x16x32_bf16(af, bw[c4][ks], acc[c4], 0, 0, 0);
            }
            const int b0 = g * MB;
#pragma unroll
            for (int c4 = 0; c4 < 4; ++c4) {
                int col = (w * 4 + c4) * 16 + lr;
#pragma unroll
                for (int reg = 0; reg < 4; ++reg) {
                    int i = lg * 4 + reg;         // C row: 0..3 = x, 4..7 = agg
                    bool doit = (col < 128) ? (i < 4) : (i >= 4 && i < 8);
                    if (doit) {
                        float v = fmaxf(acc[c4][reg], 0.f);
                        out[(size_t)(b0 + (i & 3)) * 256 + col] = v;
                    }
                }
            }
        }

        if (!more) break;
        g = gn;
        p ^= 1;
    }
}

extern "C" void kernel_launch(void* const* d_in, const int* in_sizes, int n_in,
                              void* d_out, int out_size, void* d_ws, size_t ws_size,
                              hipStream_t stream) {
    const float* x    = (const float*)d_in[0];
    const float* nb   = (const float*)d_in[1];
    const float* Watt = (const float*)d_in[2];
    const float* Wfcx = (const float*)d_in[3];
    const float* Wfcn = (const float*)d_in[4];
    const float* a    = (const float*)d_in[5];
    __bf16* WaT = (__bf16*)d_ws;
    __bf16* WcT = WaT + 128 * 256;
    float* o = (float*)d_out;

    prep_weights<<<256, 256, 0, stream>>>(Watt, Wfcx, Wfcn, WaT, WcT);
    gat_fused<<<GRID, 256, 0, stream>>>(x, nb, a, WaT, WcT, o);
}

// Round 7
// 139.328 us; speedup vs baseline: 1.2591x; 1.2591x over previous
//
#include <hip/hip_runtime.h>
#include <hip/hip_bf16.h>

// GAT attention aggregator, fused. B=20000, N=32, D=128, H=256, O=128.
// R7: revert to R5's 5000-block structure (persistent R6 doubled FETCH_SIZE,
// L3 thrash). Latency cuts: (1) two-phase staging — all 17 global loads
// issued before any ds_write (kills serialized vmcnt chain); (2) in-wave
// softmax (wave w owns node w) — removes att_s LDS + one barrier; 3 barriers
// total. ks-outer MFMA + reused panel regs keep VGPR well under the
// launch_bounds(256,4) cap of 128.

#define BB 20000
#define NN 32
#define DD 128
#define HH 256
#define OO 128
#define MB 4
#define ROWS 144         // 128 neib + 4 x (128..131) + 4 agg (132..135) + 8 junk
#define AG0 132

typedef __bf16 bf16x8 __attribute__((ext_vector_type(8)));
typedef __bf16 bf16x4 __attribute__((ext_vector_type(4)));
typedef float f32x4 __attribute__((ext_vector_type(4)));

template<int CTRL>
__device__ __forceinline__ float dpp_add(float v) {
    int r = __builtin_amdgcn_update_dpp(0, __builtin_bit_cast(int, v), CTRL, 0xF, 0xF, true);
    return v + __builtin_bit_cast(float, r);
}
// lane 15 of each 16-lane row ends with the row sum
__device__ __forceinline__ float red16(float v) {
    v = dpp_add<0x111>(v);
    v = dpp_add<0x112>(v);
    v = dpp_add<0x114>(v);
    v = dpp_add<0x118>(v);
    return v;
}

__global__ void prep_weights(const float* __restrict__ Watt,
                             const float* __restrict__ Wfcx,
                             const float* __restrict__ Wfcn,
                             __bf16* __restrict__ WaT,
                             __bf16* __restrict__ WcT) {
    int idx = blockIdx.x * 256 + threadIdx.x;   // 0..65535
    int half = idx >> 15;
    int j = idx & 32767;
    int c = j >> 7, k = j & 127;
    if (half == 0) {
        WaT[j] = (__bf16)Watt[k * HH + c];       // WaT[h][k] = W_att[k][h]
    } else {
        float wv = (c < OO) ? Wfcx[k * OO + c] : Wfcn[k * OO + (c - OO)];
        WcT[j] = (__bf16)wv;                     // WcT[c][k]
    }
}

__launch_bounds__(256, 4)
__global__ void gat_fused(const float* __restrict__ x,
                          const float* __restrict__ neibs,
                          const float* __restrict__ a,
                          const __bf16* __restrict__ WaT,
                          const __bf16* __restrict__ WcT,
                          float* __restrict__ out) {
    __shared__ __bf16 rowsS[ROWS * 128];         // 36,864 B, XOR-swizzled rows
    __shared__ float e_part[4][ROWS];            //  2,304 B

    const int tid = threadIdx.x;
    const int w   = tid >> 6;      // wave id == local node id
    const int l   = tid & 63;
    const int lr  = l & 15;
    const int lg  = l >> 4;
    const int b0  = blockIdx.x * MB;
    char* rbase = (char*)rowsS;

    // staging: row = it*8 + (tid>>5); byte off (row*256 + 2k) ^ ((row&7)<<4)
    const int stbase = (tid >> 5) * 256 + ((8 * (tid & 31)) ^ ((tid >> 5) << 4));
    int abase[4];
#pragma unroll
    for (int ks = 0; ks < 4; ++ks)
        abase[ks] = lr * 256 + ((ks * 64 + lg * 16) ^ ((lr & 7) << 4));

    // ---- two-phase staging: issue ALL loads, then convert+write ----
    float4 nv[16], xv;
    {
        const float4* np4 = (const float4*)(neibs + (size_t)b0 * NN * DD);
#pragma unroll
        for (int it = 0; it < 16; ++it) nv[it] = np4[it * 256 + tid];
        if (tid < 128) xv = ((const float4*)(x + (size_t)b0 * DD))[tid];
    }
    float aX[4], aN[4];
#pragma unroll
    for (int c4 = 0; c4 < 4; ++c4) {
        int col = (w * 4 + c4) * 16 + lr;
        aX[c4] = a[col];
        aN[c4] = a[HH + col];
    }
#pragma unroll
    for (int it = 0; it < 16; ++it) {
        bf16x4 s = { (__bf16)nv[it].x, (__bf16)nv[it].y, (__bf16)nv[it].z, (__bf16)nv[it].w };
        *(bf16x4*)(rbase + stbase + it * 2048) = s;
    }
    if (tid < 128) {                              // x rows 128..131
        bf16x4 s = { (__bf16)xv.x, (__bf16)xv.y, (__bf16)xv.z, (__bf16)xv.w };
        *(bf16x4*)(rbase + stbase + 32768) = s;
    }

    // W_att panel loads issue here — latency overlaps other waves' staging tail
    bf16x8 bw[4][4];
#pragma unroll
    for (int c4 = 0; c4 < 4; ++c4)
#pragma unroll
        for (int ks = 0; ks < 4; ++ks)
            bw[c4][ks] = *(const bf16x8*)(WaT + ((w * 4 + c4) * 16 + lr) * 128 + ks * 32 + lg * 8);

    __syncthreads();                              // B1: staged rows visible

    // ---- score: [144x128] @ WaT^T, fused lrelu(.01)*a + DPP reduce ----
#pragma unroll
    for (int rt = 0; rt < 9; ++rt) {
        f32x4 acc[4];
#pragma unroll
        for (int c4 = 0; c4 < 4; ++c4) acc[c4] = (f32x4){0.f, 0.f, 0.f, 0.f};
#pragma unroll
        for (int ks = 0; ks < 4; ++ks) {
            bf16x8 af = *(const bf16x8*)(rbase + abase[ks] + rt * 4096);
#pragma unroll
            for (int c4 = 0; c4 < 4; ++c4)
                acc[c4] = __builtin_amdgcn_mfma_f32_16x16x32_bf16(af, bw[c4][ks], acc[c4], 0, 0, 0);
        }
        float ep[4] = {0.f, 0.f, 0.f, 0.f};
#pragma unroll
        for (int c4 = 0; c4 < 4; ++c4) {
            float av = (rt == 8) ? aX[c4] : aN[c4];
#pragma unroll
            for (int i = 0; i < 4; ++i) {
                float v = acc[c4][i];
                float lv = fmaxf(v, 0.f) + 0.01f * fminf(v, 0.f);
                ep[i] = fmaf(lv, av, ep[i]);
            }
        }
#pragma unroll
        for (int i = 0; i < 4; ++i) ep[i] = red16(ep[i]);
        if (lr == 15) {
            f32x4 st = { ep[0], ep[1], ep[2], ep[3] };
            *(f32x4*)((char*)&e_part[w][0] + rt * 64 + lg * 16) = st;
        }
    }
    __syncthreads();                              // B2: e_part complete

    // ---- in-wave softmax: wave w handles node w; att stays in registers ----
    float att;
    {
        const int nl = l & 31;                    // halves duplicate, both valid
        const int idx = w * 32 + nl;
        float sn = e_part[0][idx] + e_part[1][idx] + e_part[2][idx] + e_part[3][idx];
        const int xr = 128 + w;
        float sx = e_part[0][xr] + e_part[1][xr] + e_part[2][xr] + e_part[3][xr];
        float e = sx + sn;
        e = (e > 0.f) ? e : 0.2f * e;
        float mx = e;
#pragma unroll
        for (int m = 16; m >= 1; m >>= 1) mx = fmaxf(mx, __shfl_xor(mx, m, 32));
        float ex = __expf(e - mx);
        float sum = ex;
#pragma unroll
        for (int m = 16; m >= 1; m >>= 1) sum += __shfl_xor(sum, m, 32);
        att = ex / sum;
    }

    // WcT panel loads issue here — L2 latency hides under aggregation
    bf16x8 bff[4][4];
#pragma unroll
    for (int c4 = 0; c4 < 4; ++c4)
#pragma unroll
        for (int ks = 0; ks < 4; ++ks)
            bff[c4][ks] = *(const bf16x8*)(WcT + ((w * 4 + c4) * 16 + lr) * 128 + ks * 32 + lg * 8);

    // ---- aggregation: wave w = node w; half-waves take even/odd neighbors ----
    {
        const int half = l >> 5, li = l & 31;
        const int agbase = w * 8192 + 256 * half + ((8 * li) ^ (half << 4));
        float ag[4] = {0.f, 0.f, 0.f, 0.f};
#pragma unroll
        for (int i = 0; i < 16; ++i) {
            float wv = __shfl(att, 2 * i + half, 64);
            bf16x4 v = *(const bf16x4*)(rbase + (agbase ^ ((2 * i & 7) << 4)) + 512 * i);
#pragma unroll
            for (int j = 0; j < 4; ++j) ag[j] = fmaf(wv, (float)v[j], ag[j]);
        }
#pragma unroll
        for (int j = 0; j < 4; ++j) ag[j] += __shfl_xor(ag[j], 32);
        if (half == 0) {
            int row = AG0 + w;                    // row&7 = 4+w
            int off = row * 256 + ((8 * li) ^ ((row & 7) << 4));
            bf16x4 s = { (__bf16)ag[0], (__bf16)ag[1], (__bf16)ag[2], (__bf16)ag[3] };
            *(bf16x4*)(rbase + off) = s;
        }
    }
    __syncthreads();                              // B3: agg rows visible

    // ---- final matmul: [x;agg;junk](16x128) @ WcT^T(128x256), masked store ----
    {
        f32x4 acc[4];
#pragma unroll
        for (int c4 = 0; c4 < 4; ++c4) acc[c4] = (f32x4){0.f, 0.f, 0.f, 0.f};
#pragma unroll
        for (int ks = 0; ks < 4; ++ks) {
            bf16x8 af = *(const bf16x8*)(rbase + abase[ks] + 32768);  // rows 128+lr
#pragma unroll
            for (int c4 = 0; c4 < 4; ++c4)
                acc[c4] = __builtin_amdgcn_mfma_f32_16x16x32_bf16(af, bff[c4][ks], acc[c4], 0, 0, 0);
        }
#pragma unroll
        for (int c4 = 0; c4 < 4; ++c4) {
            int col = (w * 4 + c4) * 16 + lr;
#pragma unroll
            for (int reg = 0; reg < 4; ++reg) {
                int i = lg * 4 + reg;             // C row: 0..3 = x, 4..7 = agg
                bool doit = (col < 128) ? (i < 4) : (i >= 4 && i < 8);
                if (doit) {
                    float v = fmaxf(acc[c4][reg], 0.f);
                    out[(size_t)(b0 + (i & 3)) * 256 + col] = v;
                }
            }
        }
    }
}

extern "C" void kernel_launch(void* const* d_in, const int* in_sizes, int n_in,
                              void* d_out, int out_size, void* d_ws, size_t ws_size,
                              hipStream_t stream) {
    const float* x    = (const float*)d_in[0];
    const float* nb   = (const float*)d_in[1];
    const float* Watt = (const float*)d_in[2];
    const float* Wfcx = (const float*)d_in[3];
    const float* Wfcn = (const float*)d_in[4];
    const float* a    = (const float*)d_in[5];
    __bf16* WaT = (__bf16*)d_ws;
    __bf16* WcT = WaT + 128 * 256;
    float* o = (float*)d_out;

    prep_weights<<<256, 256, 0, stream>>>(Watt, Wfcx, Wfcn, WaT, WcT);
    gat_fused<<<BB / MB, 256, 0, stream>>>(x, nb, a, WaT, WcT, o);
}

// Round 8
// 132.124 us; speedup vs baseline: 1.3278x; 1.0545x over previous
//
#include <hip/hip_runtime.h>
#include <hip/hip_bf16.h>

// GAT attention aggregator, fused. B=20000, N=32, D=128, H=256, O=128.
// R8: 512-thread (8-wave) blocks, MB=4, 5000 blocks. Per-wave work halved
// (32-col score slices, bw[2][4]=32 VGPR), agg = one (node,d) element per
// thread (no cross-lane combine), softmax in-wave (duplicated per wave pair),
// e_part in bf16 -> LDS 39.2 KB -> 3-4 blocks/CU at launch_bounds(512,6).

#define BB 20000
#define NN 32
#define DD 128
#define HH 256
#define OO 128
#define MB 4
#define ROWS 144         // 128 neib + 4 x (128..131) + 4 agg (132..135) + 8 junk
#define AG0 132

typedef __bf16 bf16x8 __attribute__((ext_vector_type(8)));
typedef __bf16 bf16x4 __attribute__((ext_vector_type(4)));
typedef float f32x4 __attribute__((ext_vector_type(4)));

template<int CTRL>
__device__ __forceinline__ float dpp_add(float v) {
    int r = __builtin_amdgcn_update_dpp(0, __builtin_bit_cast(int, v), CTRL, 0xF, 0xF, true);
    return v + __builtin_bit_cast(float, r);
}
// lane 15 of each 16-lane row ends with the row sum
__device__ __forceinline__ float red16(float v) {
    v = dpp_add<0x111>(v);
    v = dpp_add<0x112>(v);
    v = dpp_add<0x114>(v);
    v = dpp_add<0x118>(v);
    return v;
}

__global__ void prep_weights(const float* __restrict__ Watt,
                             const float* __restrict__ Wfcx,
                             const float* __restrict__ Wfcn,
                             __bf16* __restrict__ WaT,
                             __bf16* __restrict__ WcT) {
    int idx = blockIdx.x * 256 + threadIdx.x;   // 0..65535
    int half = idx >> 15;
    int j = idx & 32767;
    int c = j >> 7, k = j & 127;
    if (half == 0) {
        WaT[j] = (__bf16)Watt[k * HH + c];       // WaT[h][k] = W_att[k][h]
    } else {
        float wv = (c < OO) ? Wfcx[k * OO + c] : Wfcn[k * OO + (c - OO)];
        WcT[j] = (__bf16)wv;                     // WcT[c][k]
    }
}

__launch_bounds__(512, 6)
__global__ void gat_fused(const float* __restrict__ x,
                          const float* __restrict__ neibs,
                          const float* __restrict__ a,
                          const __bf16* __restrict__ WaT,
                          const __bf16* __restrict__ WcT,
                          float* __restrict__ out) {
    __shared__ __bf16 rowsS[ROWS * 128];         // 36,864 B, XOR-swizzled rows
    __shared__ __bf16 e_part[8][ROWS];           //  2,304 B

    const int tid = threadIdx.x;
    const int w   = tid >> 6;      // wave 0..7
    const int l   = tid & 63;
    const int lr  = l & 15;
    const int lg  = l >> 4;
    const int b0  = blockIdx.x * MB;
    char* rbase = (char*)rowsS;

    // staging: float4 idx = it*512 + tid; row = it*16 + (tid>>5); elem = 4*(tid&31)
    const int s = tid >> 5;                       // 0..15; row&7 = s&7 (invariant)
    const int stbase = s * 256 + ((8 * (tid & 31)) ^ ((s & 7) << 4));
    int abase[4];
#pragma unroll
    for (int ks = 0; ks < 4; ++ks)
        abase[ks] = lr * 256 + ((ks * 64 + lg * 16) ^ ((lr & 7) << 4));

    // ---- two-phase staging: 8 loads issued, then convert+write ----
    float4 nv[8], xv;
    {
        const float4* np4 = (const float4*)(neibs + (size_t)b0 * NN * DD);
#pragma unroll
        for (int it = 0; it < 8; ++it) nv[it] = np4[it * 512 + tid];
        if (tid < 128) xv = ((const float4*)(x + (size_t)b0 * DD))[tid];
    }
    float aX[2], aN[2];
#pragma unroll
    for (int c4 = 0; c4 < 2; ++c4) {
        int col = (w * 2 + c4) * 16 + lr;
        aX[c4] = a[col];
        aN[c4] = a[HH + col];
    }
#pragma unroll
    for (int it = 0; it < 8; ++it) {
        bf16x4 sv = { (__bf16)nv[it].x, (__bf16)nv[it].y, (__bf16)nv[it].z, (__bf16)nv[it].w };
        *(bf16x4*)(rbase + stbase + it * 4096) = sv;
    }
    if (tid < 128) {                              // x rows 128..131
        bf16x4 sv = { (__bf16)xv.x, (__bf16)xv.y, (__bf16)xv.z, (__bf16)xv.w };
        *(bf16x4*)(rbase + stbase + 32768) = sv;
    }

    // W_att panel (32 cols per wave), loads overlap staging tail
    bf16x8 bw[2][4];
#pragma unroll
    for (int c4 = 0; c4 < 2; ++c4)
#pragma unroll
        for (int ks = 0; ks < 4; ++ks)
            bw[c4][ks] = *(const bf16x8*)(WaT + ((w * 2 + c4) * 16 + lr) * 128 + ks * 32 + lg * 8);

    __syncthreads();                              // B1: staged rows visible

    // ---- score: 8 neib row-tiles + peeled x tile; fused lrelu(.01)*a + DPP reduce ----
#pragma unroll 1
    for (int rt = 0; rt < 8; ++rt) {
        bf16x8 af[4];
#pragma unroll
        for (int ks = 0; ks < 4; ++ks)
            af[ks] = *(const bf16x8*)(rbase + abase[ks] + rt * 4096);
        f32x4 acc[2];
#pragma unroll
        for (int c4 = 0; c4 < 2; ++c4) acc[c4] = (f32x4){0.f, 0.f, 0.f, 0.f};
#pragma unroll
        for (int ks = 0; ks < 4; ++ks)
#pragma unroll
            for (int c4 = 0; c4 < 2; ++c4)
                acc[c4] = __builtin_amdgcn_mfma_f32_16x16x32_bf16(af[ks], bw[c4][ks], acc[c4], 0, 0, 0);
        float ep[4] = {0.f, 0.f, 0.f, 0.f};
#pragma unroll
        for (int c4 = 0; c4 < 2; ++c4)
#pragma unroll
            for (int i = 0; i < 4; ++i) {
                float v = acc[c4][i];
                float lv = fmaxf(v, 0.f) + 0.01f * fminf(v, 0.f);
                ep[i] = fmaf(lv, aN[c4], ep[i]);
            }
#pragma unroll
        for (int i = 0; i < 4; ++i) ep[i] = red16(ep[i]);
        if (lr == 15) {
            bf16x4 st = { (__bf16)ep[0], (__bf16)ep[1], (__bf16)ep[2], (__bf16)ep[3] };
            *(bf16x4*)((char*)e_part + w * (2 * ROWS) + rt * 32 + lg * 8) = st;
        }
    }
    {   // peeled x tile (rows 128..143; only lg=0 rows meaningful, rest junk->unused)
        bf16x8 af[4];
#pragma unroll
        for (int ks = 0; ks < 4; ++ks)
            af[ks] = *(const bf16x8*)(rbase + abase[ks] + 32768);
        f32x4 acc[2];
#pragma unroll
        for (int c4 = 0; c4 < 2; ++c4) acc[c4] = (f32x4){0.f, 0.f, 0.f, 0.f};
#pragma unroll
        for (int ks = 0; ks < 4; ++ks)
#pragma unroll
            for (int c4 = 0; c4 < 2; ++c4)
                acc[c4] = __builtin_amdgcn_mfma_f32_16x16x32_bf16(af[ks], bw[c4][ks], acc[c4], 0, 0, 0);
        float ep[4] = {0.f, 0.f, 0.f, 0.f};
#pragma unroll
        for (int c4 = 0; c4 < 2; ++c4)
#pragma unroll
            for (int i = 0; i < 4; ++i) {
                float v = acc[c4][i];
                float lv = fmaxf(v, 0.f) + 0.01f * fminf(v, 0.f);
                ep[i] = fmaf(lv, aX[c4], ep[i]);
            }
#pragma unroll
        for (int i = 0; i < 4; ++i) ep[i] = red16(ep[i]);
        if (lr == 15) {
            bf16x4 st = { (__bf16)ep[0], (__bf16)ep[1], (__bf16)ep[2], (__bf16)ep[3] };
            *(bf16x4*)((char*)e_part + w * (2 * ROWS) + 256 + lg * 8) = st;
        }
    }
    __syncthreads();                              // B2: e_part complete

    // ---- in-wave softmax: wave w handles node w&3 (pairs duplicate) ----
    const int node = w & 3;
    float att;
    {
        const int nl = l & 31;
        const int idx = node * 32 + nl;
        const int xr = 128 + node;
        float e = 0.f;
#pragma unroll
        for (int wv = 0; wv < 8; ++wv)
            e += (float)e_part[wv][idx] + (float)e_part[wv][xr];
        e = (e > 0.f) ? e : 0.2f * e;
        float mx = e;
#pragma unroll
        for (int m = 16; m >= 1; m >>= 1) mx = fmaxf(mx, __shfl_xor(mx, m, 32));
        float ex = __expf(e - mx);
        float sum = ex;
#pragma unroll
        for (int m = 16; m >= 1; m >>= 1) sum += __shfl_xor(sum, m, 32);
        att = ex / sum;
    }

    // WcT panel loads issue here — latency hides under aggregation
    bf16x8 bff[2][4];
#pragma unroll
    for (int c4 = 0; c4 < 2; ++c4)
#pragma unroll
        for (int ks = 0; ks < 4; ++ks)
            bff[c4][ks] = *(const bf16x8*)(WcT + ((w * 2 + c4) * 16 + lr) * 128 + ks * 32 + lg * 8);

    // ---- aggregation: one output per thread: (node, d) ----
    {
        const int d = ((w >> 2) << 6) + l;        // 0..127
        const int agb = node * 8192 + 2 * d;      // row=node*32+n -> +n*256, ^ (n&7)<<4
        float ag = 0.f;
#pragma unroll
        for (int n = 0; n < 32; ++n) {
            float wv = __shfl(att, n);            // att for neighbor n (lane n)
            __bf16 v = *(const __bf16*)(rbase + (((agb + n * 256)) ^ ((n & 7) << 4)));
            ag = fmaf(wv, (float)v, ag);
        }
        int row = AG0 + node;                     // row&7 = 4+node
        int off = row * 256 + ((2 * d) ^ ((row & 7) << 4));
        *(__bf16*)(rbase + off) = (__bf16)ag;
    }
    __syncthreads();                              // B3: agg rows visible

    // ---- final matmul: [x;agg;junk](16x128) @ WcT^T(128x256), masked store ----
    {
        bf16x8 af[4];
#pragma unroll
        for (int ks = 0; ks < 4; ++ks)
            af[ks] = *(const bf16x8*)(rbase + abase[ks] + 32768);   // rows 128+lr
        f32x4 acc[2];
#pragma unroll
        for (int c4 = 0; c4 < 2; ++c4) acc[c4] = (f32x4){0.f, 0.f, 0.f, 0.f};
#pragma unroll
        for (int ks = 0; ks < 4; ++ks)
#pragma unroll
            for (int c4 = 0; c4 < 2; ++c4)
                acc[c4] = __builtin_amdgcn_mfma_f32_16x16x32_bf16(af[ks], bff[c4][ks], acc[c4], 0, 0, 0);
#pragma unroll
        for (int c4 = 0; c4 < 2; ++c4) {
            int col = (w * 2 + c4) * 16 + lr;
#pragma unroll
            for (int reg = 0; reg < 4; ++reg) {
                int i = lg * 4 + reg;             // C row: 0..3 = x, 4..7 = agg
                bool doit = (col < 128) ? (i < 4) : (i >= 4 && i < 8);
                if (doit) {
                    float v = fmaxf(acc[c4][reg], 0.f);
                    out[(size_t)(b0 + (i & 3)) * 256 + col] = v;
                }
            }
        }
    }
}

extern "C" void kernel_launch(void* const* d_in, const int* in_sizes, int n_in,
                              void* d_out, int out_size, void* d_ws, size_t ws_size,
                              hipStream_t stream) {
    const float* x    = (const float*)d_in[0];
    const float* nb   = (const float*)d_in[1];
    const float* Watt = (const float*)d_in[2];
    const float* Wfcx = (const float*)d_in[3];
    const float* Wfcn = (const float*)d_in[4];
    const float* a    = (const float*)d_in[5];
    __bf16* WaT = (__bf16*)d_ws;
    __bf16* WcT = WaT + 128 * 256;
    float* o = (float*)d_out;

    prep_weights<<<256, 256, 0, stream>>>(Watt, Wfcx, Wfcn, WaT, WcT);
    gat_fused<<<BB / MB, 512, 0, stream>>>(x, nb, a, WaT, WcT, o);
}